// Round 10
// baseline (1532.262 us; speedup 1.0000x reference)
//
#include <hip/hip_runtime.h>
#include <math.h>

// Problem constants (SSMDecoder: B=8, T=1024, S=128, M=512, D=512, N=16, L=3)
#define R_  8192
#define T_  1024
#define B_  8
#define S_  128
#define D_  512
#define N_  16
#define MV_ 20
#define NA_ 8
#define MM_ 512

#define TC  4
#define LCH 256
#define TS  32
#define DB  8
#define TP  36
#define KP  40

typedef __attribute__((ext_vector_type(8))) short short8;
typedef __attribute__((ext_vector_type(4))) float f32x4;

static __device__ __forceinline__ float sigmoidf_(float x) {
  return 1.f / (1.f + __expf(-x));
}
// packed split: u32 = (hi_bf16 << 16) | lo_bf16  (hi = RN, lo = truncated residual)
static __device__ __forceinline__ unsigned pack1(float v) {
  unsigned u = __float_as_uint(v);
  unsigned r = (u + 0x7fffu + ((u >> 16) & 1u)) & 0xffff0000u;
  float lof = v - __uint_as_float(r);
  return r | (__float_as_uint(lof) >> 16);
}
static __device__ __forceinline__ float recon1(unsigned u) {
  return __uint_as_float(u & 0xffff0000u) + __uint_as_float(u << 16);
}
static __device__ __forceinline__ void split2(float x0, float x1,
                                              unsigned& hp, unsigned& lp) {
  unsigned u0 = __float_as_uint(x0), u1 = __float_as_uint(x1);
  unsigned r0 = u0 + 0x7fffu + ((u0 >> 16) & 1u);
  unsigned r1 = u1 + 0x7fffu + ((u1 >> 16) & 1u);
  hp = __builtin_amdgcn_perm(r1, r0, 0x07060302u);
  float l0 = x0 - __uint_as_float(r0 & 0xffff0000u);
  float l1 = x1 - __uint_as_float(r1 & 0xffff0000u);
  lp = __builtin_amdgcn_perm(__float_as_uint(l1), __float_as_uint(l0),
                             0x07060302u);
}

// ---------------------------------------------------------------------------
// Split-bf16 MFMA NT GEMM. A packed-u32 split; W pre-split ushort hi/lo.
// C ≈ Ah·Wh + Ah·Wl + Al·Wh. Tile 128 x BN, BK=32, software-pipelined loads.
// act: 0 C fp32, 2 sigmoid->C, 3 dt-fused (softplus->spout; B/C->aux),
//      4 heads (q->C; act->aux1; var->aux2), 5 Win (x->spout; z->aux2)
// ---------------------------------------------------------------------------
template<int BN>
__global__ void __launch_bounds__(256) gemm_bb(
    const unsigned* __restrict__ Asp,
    const unsigned short* __restrict__ Wh, const unsigned short* __restrict__ Wl,
    const float* __restrict__ bias,
    const float* __restrict__ bbias,
    float* __restrict__ C, int ldc,
    int K, int act,
    float* __restrict__ aux1, float* __restrict__ aux2,
    unsigned* __restrict__ spout)
{
  __shared__ unsigned short Ah[128 * KP], Al[128 * KP];
  __shared__ unsigned short Bh[BN * KP],  Bl[BN * KP];
  const int tid = threadIdx.x;
  const int m0 = blockIdx.y << 7;
  const int n0 = blockIdx.x * BN;
  const int lane = tid & 63;
  const int widx = tid >> 6;
  const int wm = (widx & 1) << 6;
  const int wn = (widx >> 1) * (BN >> 1);
  const int lr = lane & 15, quad = lane >> 4;
  const int NT = BN >> 5;

  const int arow = tid >> 1, akoff = (tid & 1) << 4;   // 16 elems / thread
  const unsigned* ap = Asp + (size_t)(m0 + arow) * K + akoff;
  int brow, bkoff;
  if (BN == 128) { brow = tid >> 1; bkoff = (tid & 1) << 4; }
  else           { brow = tid >> 2; bkoff = (tid & 3) << 3; }
  const unsigned short* wph = Wh + (size_t)(n0 + brow) * K + bkoff;
  const unsigned short* wpl = Wl + (size_t)(n0 + brow) * K + bkoff;

  f32x4 acc[4][4];
#pragma unroll
  for (int mt = 0; mt < 4; ++mt)
#pragma unroll
    for (int nt = 0; nt < NT; ++nt)
      acc[mt][nt] = (f32x4){0.f, 0.f, 0.f, 0.f};

  // preload k0 = 0
  uint4 aC[4], bhC[2], blC[2];
#pragma unroll
  for (int i = 0; i < 4; ++i) aC[i] = *(const uint4*)(ap + (i << 2));
  bhC[0] = *(const uint4*)(wph);
  blC[0] = *(const uint4*)(wpl);
  if (BN == 128) {
    bhC[1] = *(const uint4*)(wph + 8);
    blC[1] = *(const uint4*)(wpl + 8);
  }

  for (int k0 = 0; k0 < K; k0 += 32) {
    __syncthreads();
    // stage A: de-interleave packed -> hi/lo via v_perm
    {
      unsigned au[16] = {aC[0].x, aC[0].y, aC[0].z, aC[0].w,
                         aC[1].x, aC[1].y, aC[1].z, aC[1].w,
                         aC[2].x, aC[2].y, aC[2].z, aC[2].w,
                         aC[3].x, aC[3].y, aC[3].z, aC[3].w};
#pragma unroll
      for (int g = 0; g < 2; ++g) {
        unsigned h4[4], l4[4];
#pragma unroll
        for (int p = 0; p < 4; ++p) {
          unsigned u0 = au[g * 8 + 2 * p], u1 = au[g * 8 + 2 * p + 1];
          h4[p] = __builtin_amdgcn_perm(u1, u0, 0x07060302u);  // hi16 pair
          l4[p] = __builtin_amdgcn_perm(u1, u0, 0x05040100u);  // lo16 pair
        }
        *(uint4*)&Ah[arow * KP + akoff + (g << 3)] = make_uint4(h4[0], h4[1], h4[2], h4[3]);
        *(uint4*)&Al[arow * KP + akoff + (g << 3)] = make_uint4(l4[0], l4[1], l4[2], l4[3]);
      }
    }
    *(uint4*)&Bh[brow * KP + bkoff] = bhC[0];
    *(uint4*)&Bl[brow * KP + bkoff] = blC[0];
    if (BN == 128) {
      *(uint4*)&Bh[brow * KP + bkoff + 8] = bhC[1];
      *(uint4*)&Bl[brow * KP + bkoff + 8] = blC[1];
    }
    __syncthreads();

    // prefetch next iteration's globals (overlap with frag reads + MFMA)
    if (k0 + 32 < K) {
      int kn = k0 + 32;
#pragma unroll
      for (int i = 0; i < 4; ++i) aC[i] = *(const uint4*)(ap + kn + (i << 2));
      bhC[0] = *(const uint4*)(wph + kn);
      blC[0] = *(const uint4*)(wpl + kn);
      if (BN == 128) {
        bhC[1] = *(const uint4*)(wph + kn + 8);
        blC[1] = *(const uint4*)(wpl + kn + 8);
      }
    }

    short8 fah[4], fal[4], fbh[4], fbl[4];
#pragma unroll
    for (int mt = 0; mt < 4; ++mt) {
      int r = (wm + mt * 16 + lr) * KP + quad * 8;
      fah[mt] = *(const short8*)&Ah[r];
      fal[mt] = *(const short8*)&Al[r];
    }
#pragma unroll
    for (int nt = 0; nt < NT; ++nt) {
      int r = (wn + nt * 16 + lr) * KP + quad * 8;
      fbh[nt] = *(const short8*)&Bh[r];
      fbl[nt] = *(const short8*)&Bl[r];
    }
#pragma unroll
    for (int mt = 0; mt < 4; ++mt)
#pragma unroll
      for (int nt = 0; nt < NT; ++nt) {
        acc[mt][nt] = __builtin_amdgcn_mfma_f32_16x16x32_bf16(
            fah[mt], fbl[nt], acc[mt][nt], 0, 0, 0);
        acc[mt][nt] = __builtin_amdgcn_mfma_f32_16x16x32_bf16(
            fal[mt], fbh[nt], acc[mt][nt], 0, 0, 0);
        acc[mt][nt] = __builtin_amdgcn_mfma_f32_16x16x32_bf16(
            fah[mt], fbh[nt], acc[mt][nt], 0, 0, 0);
      }
  }

  const int bb = m0 >> 10;
#pragma unroll
  for (int mt = 0; mt < 4; ++mt)
#pragma unroll
    for (int nt = 0; nt < NT; ++nt) {
      int ncol = n0 + wn + nt * 16 + lr;
      float bv = bias ? bias[ncol] : 0.f;
      if (bbias) bv += bbias[(size_t)bb * ldc + ncol];
#pragma unroll
      for (int reg = 0; reg < 4; ++reg) {
        int m = m0 + wm + mt * 16 + quad * 4 + reg;
        float v = acc[mt][nt][reg] + bv;
        if (act == 0) {
          C[(size_t)m * ldc + ncol] = v;
        } else if (act == 2) {
          C[(size_t)m * ldc + ncol] = sigmoidf_(v);
        } else if (act == 3) {
          if (ncol < 512) {
            float sv = (v > 20.f) ? v : log1pf(__expf(v));
            spout[(size_t)m * 512 + ncol] = pack1(sv);
          }
          else if (ncol < 528) aux1[(size_t)m * 16 + (ncol - 512)] = v;
          else if (ncol < 544) aux2[(size_t)m * 16 + (ncol - 528)] = v;
        } else if (act == 4) {
          if (ncol < 512)      C[(size_t)m * ldc + ncol] = v;
          else if (ncol < 520) aux1[(size_t)m * 8 + (ncol - 512)] = v;
          else if (ncol < 540) aux2[(size_t)m * 20 + (ncol - 520)] = v;
        } else {               // act == 5 (Win)
          if (ncol < 512)      spout[(size_t)m * 512 + ncol] = pack1(v);
          else                 aux2[(size_t)m * 512 + (ncol - 512)] = v;   // z
        }
      }
    }
}

// ---------------------------------------------------------------------------
// Weight / activation conversion kernels.
// ---------------------------------------------------------------------------
static __device__ __forceinline__ void wcvt_body(
    int gid, const float* __restrict__ W, int ldw,
    unsigned short* __restrict__ hi, unsigned short* __restrict__ lo)
{
  int base = gid << 3;
  int r = base >> 9, c = base & 511;
  const float* p = W + (size_t)r * ldw + c;
  float4 a0 = *(const float4*)p, a1 = *(const float4*)(p + 4);
  float af[8] = {a0.x, a0.y, a0.z, a0.w, a1.x, a1.y, a1.z, a1.w};
  unsigned h4[4], l4[4];
#pragma unroll
  for (int p2 = 0; p2 < 4; ++p2) split2(af[2 * p2], af[2 * p2 + 1], h4[p2], l4[p2]);
  *(uint4*)&hi[(size_t)r * 512 + c] = make_uint4(h4[0], h4[1], h4[2], h4[3]);
  *(uint4*)&lo[(size_t)r * 512 + c] = make_uint4(l4[0], l4[1], l4[2], l4[3]);
}

static __device__ __forceinline__ void pack_body(
    int gid, unsigned short* __restrict__ hi, unsigned short* __restrict__ lo,
    float* __restrict__ bd,
    const float* __restrict__ w0, const float* __restrict__ b0,
    const float* __restrict__ w1, const float* __restrict__ b1,
    const float* __restrict__ w2, const float* __restrict__ b2,
    int n1, int n2)
{
  int base = gid << 3;
  int r = base >> 9, c = base & 511;
  const float* src = nullptr;
  if (r < 512)                 src = w0 + (size_t)r * 512 + c;
  else if (r < 512 + n1)       src = w1 + (size_t)(r - 512) * 512 + c;
  else if (r < 512 + n1 + n2)  src = w2 + (size_t)(r - 512 - n1) * 512 + c;
  float af[8] = {0.f};
  if (src) {
    float4 a0 = *(const float4*)src, a1 = *(const float4*)(src + 4);
    af[0]=a0.x; af[1]=a0.y; af[2]=a0.z; af[3]=a0.w;
    af[4]=a1.x; af[5]=a1.y; af[6]=a1.z; af[7]=a1.w;
  }
  unsigned h4[4], l4[4];
#pragma unroll
  for (int p2 = 0; p2 < 4; ++p2) split2(af[2 * p2], af[2 * p2 + 1], h4[p2], l4[p2]);
  *(uint4*)&hi[(size_t)r * 512 + c] = make_uint4(h4[0], h4[1], h4[2], h4[3]);
  *(uint4*)&lo[(size_t)r * 512 + c] = make_uint4(l4[0], l4[1], l4[2], l4[3]);
  if (c == 0) {
    float bvv = 0.f;
    if (r < 512)                 bvv = b0[r];
    else if (r < 512 + n1)       bvv = b1[r - 512];
    else if (r < 512 + n1 + n2)  bvv = b2[r - 512 - n1];
    bd[r] = bvv;
  }
}

__global__ void cvt_layerA(const float* __restrict__ Win_l,
                           const float* __restrict__ Wdt_l, const float* __restrict__ b_dt_l,
                           const float* __restrict__ WB_l, const float* __restrict__ b_B_l,
                           const float* __restrict__ WC_l, const float* __restrict__ b_C_l,
                           unsigned short* WinH, unsigned short* WinL,
                           unsigned short* WpkH, unsigned short* WpkL, float* bpk)
{
  int blk = blockIdx.x;
  if (blk < 256)
    wcvt_body(blk * 256 + threadIdx.x, Win_l, 512, WinH, WinL);
  else
    pack_body((blk - 256) * 256 + threadIdx.x, WpkH, WpkL, bpk,
              Wdt_l, b_dt_l, WB_l, b_B_l, WC_l, b_C_l, 16, 16);
}

__global__ void cvt_layerB(const float* __restrict__ Wout_l,
                           const float* __restrict__ Wg_l,
                           unsigned short* WsqH, unsigned short* WsqL,
                           unsigned short* WgH, unsigned short* WgL)
{
  int blk = blockIdx.x;
  if (blk < 128)
    wcvt_body(blk * 256 + threadIdx.x, Wout_l, 512, WsqH, WsqL);
  else
    wcvt_body((blk - 128) * 256 + threadIdx.x, Wg_l, 1024, WgH, WgL);
}

__global__ void cvt_heads(const float* __restrict__ Wq, const float* __restrict__ b_q,
                          const float* __restrict__ Wa, const float* __restrict__ b_a,
                          const float* __restrict__ Wv, const float* __restrict__ b_v,
                          const float* __restrict__ Wk,
                          unsigned short* WpkH, unsigned short* WpkL, float* bpk,
                          unsigned short* WsqH, unsigned short* WsqL)
{
  int blk = blockIdx.x;
  if (blk < 144)
    pack_body(blk * 256 + threadIdx.x, WpkH, WpkL, bpk,
              Wq, b_q, Wa, b_a, Wv, b_v, NA_, MV_);
  else
    wcvt_body((blk - 144) * 256 + threadIdx.x, Wk, 512, WsqH, WsqL);
}

__global__ void wcvt(const float* __restrict__ W, int ldw,
                     unsigned short* __restrict__ hi, unsigned short* __restrict__ lo)
{
  wcvt_body(blockIdx.x * 256 + threadIdx.x, W, ldw, hi, lo);
}

// fp32 [rows][lda] -> packed-split u32 [rows][512]
__global__ void acvt(const float* __restrict__ A, int lda, unsigned* __restrict__ sp)
{
  int gid = blockIdx.x * 256 + threadIdx.x;
  int base = gid << 2;
  int r = base >> 9, c = base & 511;
  float4 a = *(const float4*)(A + (size_t)r * lda + c);
  uint4 o;
  o.x = pack1(a.x); o.y = pack1(a.y); o.z = pack1(a.z); o.w = pack1(a.w);
  *(uint4*)&sp[(size_t)r * 512 + c] = o;
}

// ---------------------------------------------------------------------------
// Batched scores (fp32): out[b,t,s] = dot(q,k)/sqrt(D); masked -> -1e30.
// ---------------------------------------------------------------------------
#define BM 64
#define SBN 64
#define SBK 16

__global__ void __launch_bounds__(256) scores_kernel(
    const float* __restrict__ q, const float* __restrict__ kmat,
    const int* __restrict__ mask, float* __restrict__ out)
{
  __shared__ __align__(16) float As[SBK][BM + 4];
  __shared__ __align__(16) float Ws[SBK][SBN + 4];
  const int b = blockIdx.z;
  const float* A = q + (size_t)b * T_ * D_;
  const float* W = kmat + (size_t)b * S_ * D_;
  const int tid = threadIdx.x;
  const int m0 = blockIdx.y * BM;
  const int n0 = blockIdx.x * SBN;
  const int tx = tid & 15, ty = tid >> 4;
  const int lr = tid >> 2;
  const int lk = (tid & 3) << 2;
  float acc[4][4] = {{0.f}};
  const float* aptr = A + (size_t)(m0 + lr) * D_ + lk;
  const float* wptr = W + (size_t)(n0 + lr) * D_ + lk;

  for (int k0 = 0; k0 < D_; k0 += SBK) {
    float4 av = *(const float4*)(aptr + k0);
    float4 wv = *(const float4*)(wptr + k0);
    __syncthreads();
    As[lk + 0][lr] = av.x; As[lk + 1][lr] = av.y;
    As[lk + 2][lr] = av.z; As[lk + 3][lr] = av.w;
    Ws[lk + 0][lr] = wv.x; Ws[lk + 1][lr] = wv.y;
    Ws[lk + 2][lr] = wv.z; Ws[lk + 3][lr] = wv.w;
    __syncthreads();
#pragma unroll
    for (int kk = 0; kk < SBK; ++kk) {
      float4 a4 = *(const float4*)&As[kk][ty << 2];
      float4 b4 = *(const float4*)&Ws[kk][tx << 2];
      float a_[4] = {a4.x, a4.y, a4.z, a4.w};
      float b_[4] = {b4.x, b4.y, b4.z, b4.w};
#pragma unroll
      for (int i = 0; i < 4; ++i)
#pragma unroll
        for (int j = 0; j < 4; ++j)
          acc[i][j] = fmaf(a_[i], b_[j], acc[i][j]);
    }
  }

  const float scale = 0.044194173824159216f;
#pragma unroll
  for (int i = 0; i < 4; ++i) {
    int t = m0 + (ty << 2) + i;
#pragma unroll
    for (int j = 0; j < 4; ++j) {
      int s = n0 + (tx << 2) + j;
      float v = acc[i][j] * scale;
      if (mask[b * S_ + s] == 0) v = -1e30f;
      out[((size_t)(b * T_ + t)) * S_ + s] = v;
    }
  }
}

// ---------------------------------------------------------------------------
// Small helpers
// ---------------------------------------------------------------------------
__global__ void gemm_small(const float* __restrict__ A, int lda,
                           const float* __restrict__ W, int ldw,
                           const float* __restrict__ bias,
                           float* __restrict__ C, int ldc,
                           int MN, int Ncols, int K)
{
  int gid = blockIdx.x * 256 + threadIdx.x;
  if (gid >= MN) return;
  int r = gid / Ncols, o = gid - r * Ncols;
  const float4* a = (const float4*)(A + (size_t)r * lda);
  const float4* w = (const float4*)(W + (size_t)o * ldw);
  float acc = bias ? bias[o] : 0.f;
  int K4 = K >> 2;
  for (int k = 0; k < K4; ++k) {
    float4 av = a[k], wv = w[k];
    acc = fmaf(av.x, wv.x, fmaf(av.y, wv.y, fmaf(av.z, wv.z, fmaf(av.w, wv.w, acc))));
  }
  C[(size_t)r * ldc + o] = acc;
}

__global__ void ctx_kernel(const float* __restrict__ msum, const float* __restrict__ Wm,
                           const float* __restrict__ b_m, float* __restrict__ ctxv)
{
  int gid = blockIdx.x * 256 + threadIdx.x;
  int l = gid >> 12, b = (gid >> 9) & 7, dd = gid & 511;
  const float4* a = (const float4*)(msum + b * 512);
  const float4* w = (const float4*)(Wm + ((size_t)l * 512 + dd) * 512);
  float acc = b_m[l * 512 + dd];
  for (int k = 0; k < 128; ++k) {
    float4 av = a[k], wv = w[k];
    acc = fmaf(av.x, wv.x, fmaf(av.y, wv.y, fmaf(av.z, wv.z, fmaf(av.w, wv.w, acc))));
  }
  ctxv[gid] = acc;
}

__global__ void gctx_kernel(const float* __restrict__ ctxv, const float* __restrict__ Wg,
                            const float* __restrict__ b_g, float* __restrict__ gctx)
{
  int gid = blockIdx.x * 256 + threadIdx.x;
  int l = gid >> 12, b = (gid >> 9) & 7, dd = gid & 511;
  const float4* a = (const float4*)(ctxv + ((size_t)l * 8 + b) * 512);
  const float4* w = (const float4*)(Wg + ((size_t)l * 512 + dd) * 1024 + 512);
  float acc = b_g[l * 512 + dd];
  for (int k = 0; k < 128; ++k) {
    float4 av = a[k], wv = w[k];
    acc = fmaf(av.x, wv.x, fmaf(av.y, wv.y, fmaf(av.z, wv.z, fmaf(av.w, wv.w, acc))));
  }
  gctx[gid] = acc;
}

__global__ void __launch_bounds__(256) transpose512(
    const float* __restrict__ A, float* __restrict__ At)
{
  __shared__ float tl[32][33];
  int i0 = blockIdx.y * 32, j0 = blockIdx.x * 32;
  int li = threadIdx.x & 31, lj = threadIdx.x >> 5;
#pragma unroll
  for (int k = 0; k < 4; ++k)
    tl[lj * 4 + k][li] = A[(size_t)(i0 + lj * 4 + k) * 512 + j0 + li];
  __syncthreads();
#pragma unroll
  for (int k = 0; k < 4; ++k)
    At[(size_t)(j0 + lj * 4 + k) * 512 + i0 + li] = tl[li][lj * 4 + k];
}

__global__ void memsum_kernel(const float* __restrict__ mem, float* __restrict__ out)
{
  int b = blockIdx.x >> 1;
  int d = ((blockIdx.x & 1) << 8) + threadIdx.x;
  const float* p = mem + (size_t)b * MM_ * D_ + d;
  float s = 0.f;
  for (int m = 0; m < MM_; ++m) s += p[(size_t)m * D_];
  out[b * D_ + d] = s * (1.f / MM_);
}

// h fp32 + packed h-split
__global__ void combine_kernel(float* __restrict__ h,
                               unsigned* __restrict__ sp,
                               const float* __restrict__ Psym,
                               const float* __restrict__ Pact,
                               const float* __restrict__ Pvar, const float* __restrict__ b2,
                               const float* __restrict__ bcomb,
                               const int* __restrict__ ta, const int* __restrict__ tg)
{
  int i = blockIdx.x * 256 + threadIdx.x;
  int r = i >> 9, j = i & 511;
  int t = r & (T_ - 1);
  int a = t ? ta[r - 1] : 0;
  float val = Pact[a * D_ + j] + bcomb[j];
  if (a == 1 || a == 2) {
    int g = t ? tg[r - 1] : 0;
    g = g < 0 ? 0 : (g > S_ - 1 ? S_ - 1 : g);
    val += Psym[((size_t)(r >> 10) * S_ + g) * D_ + j] + b2[j];
  } else if (a == 3) {
    int g = t ? tg[r - 1] : 0;
    g = g < 0 ? 0 : (g > MV_ - 1 ? MV_ - 1 : g);
    val += Pvar[g * D_ + j];
  }
  h[i] = val;
  sp[i] = pack1(val);
}

// ---------------------------------------------------------------------------
// Chunked selective scan; dt/x read from packed splits.
// ---------------------------------------------------------------------------
__global__ void __launch_bounds__(128) scan_pass1(
    const unsigned* __restrict__ xsp, const unsigned* __restrict__ dsp,
    const float* __restrict__ Bmv, const float* __restrict__ Alog,
    float* __restrict__ aprod, float* __restrict__ hend)
{
  __shared__ __align__(16) float sdtT[DB][TP];
  __shared__ __align__(16) float sxT[DB][TP];
  __shared__ __align__(16) float sB[TS][16];
  const int tid = threadIdx.x;
  const int n = tid & 15, dl = tid >> 4;
  const int c = blockIdx.x, db = blockIdx.y, b = blockIdx.z;
  const int d = (db << 3) + dl;
  const int t0 = c * LCH;
  const int lrow = tid >> 2, lc2 = (tid & 3) << 1, bc4 = (tid & 3) << 2;

  float An = -__expf(Alog[d * N_ + n]);
  float hst = 0.f, dsum = 0.f;

  for (int tt = 0; tt < LCH; tt += TS) {
    __syncthreads();
    {
      size_t gr = (size_t)b * T_ + t0 + tt + lrow;
      size_t ei = (gr << 9) + (db << 3) + lc2;
      uint2 du = *(const uint2*)&dsp[ei];
      uint2 xu = *(const uint2*)&xsp[ei];
      sdtT[lc2][lrow] = recon1(du.x); sdtT[lc2 + 1][lrow] = recon1(du.y);
      sxT[lc2][lrow]  = recon1(xu.x); sxT[lc2 + 1][lrow]  = recon1(xu.y);
      *(float4*)&sB[lrow][bc4] = *(const float4*)&Bmv[gr * N_ + bc4];
    }
    __syncthreads();
    float dtr[TS], xr[TS];
#pragma unroll
    for (int qv = 0; qv < TS / 4; ++qv) {
      *(float4*)&dtr[qv << 2] = *(const float4*)&sdtT[dl][qv << 2];
      *(float4*)&xr[qv << 2]  = *(const float4*)&sxT[dl][qv << 2];
    }
#pragma unroll
    for (int s = 0; s < TS; ++s) {
      float Bv = sB[s][n];
      float dA = __expf(An * dtr[s]);
      hst = fmaf(dA, hst, dtr[s] * xr[s] * Bv);
      dsum += dtr[s];
    }
  }
  size_t idx = (size_t)c * (B_ * D_ * N_) + ((size_t)b * D_ + d) * N_ + n;
  aprod[idx] = __expf(An * dsum);
  hend[idx]  = hst;
}

__global__ void scan_pass2(const float* __restrict__ aprod, float* __restrict__ hs)
{
  int g = blockIdx.x * 256 + threadIdx.x;
  float prev = 0.f;
  for (int c = 0; c < TC; ++c) {
    size_t idx = (size_t)c * (B_ * D_ * N_) + g;
    float a = aprod[idx], he = hs[idx];
    hs[idx] = prev;
    prev = fmaf(a, prev, he);
  }
}

#define HPAD 20

__global__ void __launch_bounds__(128) scan_pass3(
    const unsigned* __restrict__ xsp, unsigned* __restrict__ dsp,
    const float* __restrict__ zreg,
    const float* __restrict__ Bmv, const float* __restrict__ Cmv,
    const float* __restrict__ Alog, const float* __restrict__ hstart,
    const float* __restrict__ Dp)
{
  __shared__ __align__(16) float sdtT[DB][TP];   // dt in; y out (transposed)
  __shared__ __align__(16) float sxT[DB][TP];
  __shared__ __align__(16) float szT[DB][TP];
  __shared__ __align__(16) float sB[TS][16];
  __shared__ __align__(16) float sC[TS][16];
  __shared__ __align__(16) float sterm[128][HPAD];
  const int tid = threadIdx.x;
  const int n = tid & 15, dl = tid >> 4;
  const int c = blockIdx.x, db = blockIdx.y, b = blockIdx.z;
  const int d = (db << 3) + dl;
  const int t0 = c * LCH;
  const int lrow = tid >> 2, lc2 = (tid & 3) << 1, bc4 = (tid & 3) << 2;
  const int rsi = tid >> 3, rdl = tid & 7;

  float An = -__expf(Alog[d * N_ + n]);
  float Dpr = Dp[(db << 3) + rdl];
  size_t sidx = (size_t)c * (B_ * D_ * N_) + ((size_t)b * D_ + d) * N_ + n;
  float hst = hstart[sidx];

  for (int tt = 0; tt < LCH; tt += TS) {
    __syncthreads();
    {
      size_t gr = (size_t)b * T_ + t0 + tt + lrow;
      size_t ei = (gr << 9) + (db << 3) + lc2;
      uint2 du = *(const uint2*)&dsp[ei];
      uint2 xu = *(const uint2*)&xsp[ei];
      float2 z2 = *(const float2*)&zreg[ei];
      sdtT[lc2][lrow] = recon1(du.x); sdtT[lc2 + 1][lrow] = recon1(du.y);
      sxT[lc2][lrow]  = recon1(xu.x); sxT[lc2 + 1][lrow]  = recon1(xu.y);
      szT[lc2][lrow]  = z2.x; szT[lc2 + 1][lrow] = z2.y;
      *(float4*)&sB[lrow][bc4] = *(const float4*)&Bmv[gr * N_ + bc4];
      *(float4*)&sC[lrow][bc4] = *(const float4*)&Cmv[gr * N_ + bc4];
    }
    __syncthreads();
    float dtr[TS], xr[TS];
#pragma unroll
    for (int qv = 0; qv < TS / 4; ++qv) {
      *(float4*)&dtr[qv << 2] = *(const float4*)&sdtT[dl][qv << 2];
      *(float4*)&xr[qv << 2]  = *(const float4*)&sxT[dl][qv << 2];
    }
#pragma unroll
    for (int half = 0; half < 2; ++half) {
      const int hs = half << 4;
#pragma unroll
      for (int si = 0; si < 16; ++si) {
        int s = hs + si;
        float Bv = sB[s][n], Cv = sC[s][n];
        float dA = __expf(An * dtr[s]);
        hst = fmaf(dA, hst, dtr[s] * xr[s] * Bv);
        sterm[(si << 3) + dl][n] = hst * Cv;
      }
      __syncthreads();
      {
        float4 t0v = *(const float4*)&sterm[tid][0];
        float4 t1v = *(const float4*)&sterm[tid][4];
        float4 t2v = *(const float4*)&sterm[tid][8];
        float4 t3v = *(const float4*)&sterm[tid][12];
        float s16 = ((t0v.x + t0v.y) + (t0v.z + t0v.w))
                  + ((t1v.x + t1v.y) + (t1v.z + t1v.w))
                  + ((t2v.x + t2v.y) + (t2v.z + t2v.w))
                  + ((t3v.x + t3v.y) + (t3v.z + t3v.w));
        float zv = szT[rdl][hs + rsi];
        float xv = sxT[rdl][hs + rsi];
        float yv = (s16 + Dpr * xv) * (zv * sigmoidf_(zv));
        __syncthreads();
        sdtT[rdl][hs + rsi] = yv;
      }
      __syncthreads();
    }
    // store y tile as packed split (in place over dt)
    {
      size_t gr = (size_t)b * T_ + t0 + tt + lrow;
      size_t ei = (gr << 9) + (db << 3) + lc2;
      uint2 o;
      o.x = pack1(sdtT[lc2][lrow]);
      o.y = pack1(sdtT[lc2 + 1][lrow]);
      *(uint2*)&dsp[ei] = o;
    }
  }
}

// LayerNorm + packed h-split emit. mode 0: v = h + add; mode 1: v = h + add*ctx[b]
__global__ void __launch_bounds__(256) ln_kernel(
    float* __restrict__ h,
    unsigned* __restrict__ sp,
    const float* __restrict__ add,
    const float* __restrict__ ctx,
    const float* __restrict__ gw, const float* __restrict__ bw, int mode)
{
  int r = (blockIdx.x << 2) + (threadIdx.x >> 6);
  int lane = threadIdx.x & 63;
  int b = r >> 10;
  size_t base = (size_t)r * D_;
  float v[8];
#pragma unroll
  for (int k = 0; k < 8; ++k) {
    int j = lane + (k << 6);
    float x = h[base + j];
    float a = add[base + j];
    v[k] = mode ? fmaf(a, ctx[b * D_ + j], x) : (x + a);
  }
  float s = 0.f;
#pragma unroll
  for (int k = 0; k < 8; ++k) s += v[k];
#pragma unroll
  for (int o = 1; o < 64; o <<= 1) s += __shfl_xor(s, o, 64);
  float mean = s * (1.f / D_);
  float vs = 0.f;
#pragma unroll
  for (int k = 0; k < 8; ++k) { float dv = v[k] - mean; vs = fmaf(dv, dv, vs); }
#pragma unroll
  for (int o = 1; o < 64; o <<= 1) vs += __shfl_xor(vs, o, 64);
  float inv = 1.0f / sqrtf(vs * (1.f / D_) + 1e-5f);
#pragma unroll
  for (int k = 0; k < 8; ++k) {
    int j = lane + (k << 6);
    float ov = (v[k] - mean) * inv * gw[j] + bw[j];
    h[base + j] = ov;
    sp[base + j] = pack1(ov);
  }
}

// ---------------------------------------------------------------------------
extern "C" void kernel_launch(void* const* d_in, const int* in_sizes, int n_in,
                              void* d_out, int out_size, void* d_ws, size_t ws_size,
                              hipStream_t stream)
{
  const float* symbol_embeds = (const float*)d_in[0];
  const float* memory_       = (const float*)d_in[1];
  const float* action_embed  = (const float*)d_in[2];
  const float* W_arg  = (const float*)d_in[3];
  const float* b_arg  = (const float*)d_in[4];
  const float* var_embed = (const float*)d_in[5];
  const float* W_comb = (const float*)d_in[6];
  const float* b_comb = (const float*)d_in[7];
  const float* Win  = (const float*)d_in[8];
  const float* b_in = (const float*)d_in[9];
  const float* Wdt  = (const float*)d_in[10];
  const float* b_dt = (const float*)d_in[11];
  const float* Alog = (const float*)d_in[12];
  const float* WB   = (const float*)d_in[13];
  const float* b_B  = (const float*)d_in[14];
  const float* WC   = (const float*)d_in[15];
  const float* b_C  = (const float*)d_in[16];
  const float* Dp   = (const float*)d_in[17];
  const float* Wout = (const float*)d_in[18];
  const float* b_out= (const float*)d_in[19];
  const float* ssm_g= (const float*)d_in[20];
  const float* ssm_b= (const float*)d_in[21];
  const float* Wm   = (const float*)d_in[22];
  const float* b_m  = (const float*)d_in[23];
  const float* Wg   = (const float*)d_in[24];
  const float* b_g  = (const float*)d_in[25];
  const float* cn_g = (const float*)d_in[26];
  const float* cn_b = (const float*)d_in[27];
  const float* Wa   = (const float*)d_in[28];
  const float* b_a  = (const float*)d_in[29];
  const float* Wq   = (const float*)d_in[30];
  const float* b_q  = (const float*)d_in[31];
  const float* Wk   = (const float*)d_in[32];
  const float* b_k  = (const float*)d_in[33];
  const float* Wv   = (const float*)d_in[34];
  const float* b_v  = (const float*)d_in[35];
  const int* ta     = (const int*)d_in[36];
  const int* tg     = (const int*)d_in[37];
  const int* smask  = (const int*)d_in[38];
  (void)in_sizes; (void)n_in; (void)out_size; (void)ws_size;

  const size_t RD = (size_t)R_ * 512;   // 4M elements

  // ---- workspace (exactly 64 MB), 4 regions of 16 MB ----
  float* ws = (float*)d_ws;
  unsigned* xsp = (unsigned*)ws;          // region A: x packed split / regA fp32
  float* regA = ws;
  float* zreg = ws + RD;                  // region B: z fp32 / kmat
  unsigned* csp = (unsigned*)(ws + 2 * RD); // region C: h/dt/y packed split
  float* h = ws + 3 * RD;                 // region D: h fp32

  // ---- d_out scratch (1,277,952 floats) ----
  float* out     = (float*)d_out;
  float* out_act = out;
  float* out_sc  = out + (size_t)R_ * NA_;
  float* out_var = out + (size_t)R_ * (NA_ + S_);

  float* Bmv  = out;                      // 131072
  float* Cmv  = Bmv  + 131072;            // 131072
  float* aprd = Cmv  + 131072;            // 262144
  float* hend = aprd + 262144;            // 262144
  float* Wpk  = hend + 262144;            // 294912
  float* bpk  = Wpk  + 294912;            // 576
  float* msum = bpk  + 576;               // 4096
  float* ctxv = msum + 4096;              // 12288
  float* gctx = ctxv + 12288;             // 12288

  unsigned short* WpkH = (unsigned short*)Wpk;
  unsigned short* WpkL = WpkH + 294912;
  unsigned short* WinH = (unsigned short*)aprd;
  unsigned short* WinL = (unsigned short*)hend;
  unsigned short* WsqH = (unsigned short*)aprd;
  unsigned short* WsqL = WsqH + 262144;
  unsigned short* WgH  = (unsigned short*)hend;
  unsigned short* WgL  = WgH + 262144;
  unsigned short* PrepH = (unsigned short*)Bmv;
  unsigned short* PrepL = PrepH + 262144;

  float* Pact = aprd;
  float* Pvar = Pact + 4096;
  float* b2   = Pvar + 10240;
  float* M2   = hend;
  float* WargT= Wpk;

  dim3 blk(256), blk128(128);

  // ---- precompute ----
  memsum_kernel<<<16, blk, 0, stream>>>(memory_, msum);
  gemm_small<<<16, blk, 0, stream>>>(action_embed, 512, W_comb, 1024, nullptr,
                                     Pact, 512, 8 * 512, 512, 512);
  gemm_small<<<40, blk, 0, stream>>>(var_embed, 512, W_comb + 512, 1024, nullptr,
                                     Pvar, 512, 20 * 512, 512, 512);
  gemm_small<<<2, blk, 0, stream>>>(b_arg, 512, W_comb + 512, 1024, nullptr,
                                    b2, 512, 512, 512, 512);
  ctx_kernel<<<48, blk, 0, stream>>>(msum, Wm, b_m, ctxv);
  gctx_kernel<<<48, blk, 0, stream>>>(ctxv, Wg, b_g, gctx);
  transpose512<<<dim3(16, 16), blk, 0, stream>>>(W_arg, WargT);
  wcvt<<<128, blk, 0, stream>>>(WargT, 512, PrepH, PrepL);
  acvt<<<256, blk, 0, stream>>>(W_comb + 512, 1024, csp);
  // M2 = Wcb2 @ W_arg
  gemm_bb<128><<<dim3(4, 4), blk, 0, stream>>>(csp, PrepH, PrepL,
      nullptr, nullptr, M2, 512, 512, 0, nullptr, nullptr, nullptr);
  wcvt<<<128, blk, 0, stream>>>(M2, 512, PrepH, PrepL);
  acvt<<<512, blk, 0, stream>>>(symbol_embeds, 512, csp);
  // Psym = symbol @ M2^T -> regA
  gemm_bb<128><<<dim3(4, 8), blk, 0, stream>>>(csp, PrepH, PrepL,
      nullptr, nullptr, regA, 512, 512, 0, nullptr, nullptr, nullptr);
  combine_kernel<<<R_ * 512 / 256, blk, 0, stream>>>(h, csp, regA,
                                                     Pact, Pvar, b2, b_comb, ta, tg);

  // ---- layers ----
  for (int l = 0; l < 3; ++l) {
    const float* Win_l  = Win  + (size_t)l * 1024 * 512;
    const float* b_in_l = b_in + l * 1024;
    const float* Wdt_l  = Wdt  + (size_t)l * 512 * 512;
    const float* b_dt_l = b_dt + l * 512;
    const float* Alog_l = Alog + (size_t)l * 512 * 16;
    const float* WB_l   = WB   + (size_t)l * 16 * 512;
    const float* b_B_l  = b_B  + l * 16;
    const float* WC_l   = WC   + (size_t)l * 16 * 512;
    const float* b_C_l  = b_C  + l * 16;
    const float* Dp_l   = Dp   + l * 512;
    const float* Wout_l = Wout + (size_t)l * 512 * 512;
    const float* b_out_l= b_out+ l * 512;
    const float* ssm_g_l= ssm_g+ l * 512;
    const float* ssm_b_l= ssm_b+ l * 512;
    const float* Wg_l   = Wg   + (size_t)l * 512 * 1024;
    const float* cn_g_l = cn_g + l * 512;
    const float* cn_b_l = cn_b + l * 512;

    cvt_layerA<<<400, blk, 0, stream>>>(Win_l, Wdt_l, b_dt_l, WB_l, b_B_l,
                                        WC_l, b_C_l, WinH, WinL, WpkH, WpkL, bpk);
    // Win: A = h-split(csp) -> x-split(xsp) + z fp32(zreg)
    gemm_bb<128><<<dim3(8, 64), blk, 0, stream>>>(csp, WinH, WinL,
        b_in_l, nullptr, nullptr, 512, 512, 5, nullptr, zreg, xsp);
    // dt/B/C: A = x-split -> dt-split(csp), Bmv, Cmv
    gemm_bb<64><<<dim3(9, 64), blk, 0, stream>>>(xsp, WpkH, WpkL,
        bpk, nullptr, nullptr, 512, 512, 3, Bmv, Cmv, csp);
    // scan
    scan_pass1<<<dim3(TC, D_ / DB, B_), blk128, 0, stream>>>(xsp, csp,
        Bmv, Alog_l, aprd, hend);
    scan_pass2<<<B_ * D_ * N_ / 256, blk, 0, stream>>>(aprd, hend);
    scan_pass3<<<dim3(TC, D_ / DB, B_), blk128, 0, stream>>>(xsp, csp,
        zreg, Bmv, Cmv, Alog_l, hend, Dp_l);
    cvt_layerB<<<256, blk, 0, stream>>>(Wout_l, Wg_l, WsqH, WsqL, WgH, WgL);
    // resid = y-split(csp) @ Wout^T -> regA fp32
    gemm_bb<128><<<dim3(4, 64), blk, 0, stream>>>(csp, WsqH, WsqL,
        b_out_l, nullptr, regA, 512, 512, 0, nullptr, nullptr, nullptr);
    ln_kernel<<<2048, blk, 0, stream>>>(h, csp, regA, nullptr,
                                        ssm_g_l, ssm_b_l, 0);
    // gate = sigmoid(h-split @ Wg^T + gctx) -> regA fp32
    gemm_bb<128><<<dim3(4, 64), blk, 0, stream>>>(csp, WgH, WgL,
        nullptr, gctx + l * 4096, regA, 512, 512, 2, nullptr, nullptr, nullptr);
    ln_kernel<<<2048, blk, 0, stream>>>(h, csp, regA, ctxv + l * 4096,
                                        cn_g_l, cn_b_l, 1);
  }

  // ---- heads ----
  cvt_heads<<<272, blk, 0, stream>>>(Wq, b_q, Wa, b_a, Wv, b_v, Wk,
                                     WpkH, WpkL, bpk, WsqH, WsqL);
  // q/action/var: A = h-split(csp); q -> regA fp32
  gemm_bb<64><<<dim3(9, 64), blk, 0, stream>>>(csp, WpkH, WpkL,
      bpk, nullptr, regA, 512, 512, 4, out_act, out_var, nullptr);
  // symbol split -> csp (h-split dead)
  acvt<<<512, blk, 0, stream>>>(symbol_embeds, 512, csp);
  // kmat = symbol-split @ Wk^T -> zreg fp32
  gemm_bb<128><<<dim3(4, 8), blk, 0, stream>>>(csp, WsqH, WsqL,
      b_k, nullptr, zreg, 512, 512, 0, nullptr, nullptr, nullptr);
  scores_kernel<<<dim3(2, 16, 8), blk, 0, stream>>>(regA, zreg, smask, out_sc);
}

// Round 11
// 1088.881 us; speedup vs baseline: 1.4072x; 1.4072x over previous
//
#include <hip/hip_runtime.h>
#include <math.h>

// Problem constants (SSMDecoder: B=8, T=1024, S=128, M=512, D=512, N=16, L=3)
#define R_  8192
#define T_  1024
#define B_  8
#define S_  128
#define D_  512
#define N_  16
#define MV_ 20
#define NA_ 8
#define MM_ 512

#define TC  4
#define LCH 256
#define TS  32
#define DB  8
#define TP  36
#define KP  40

typedef __attribute__((ext_vector_type(8))) short short8;
typedef __attribute__((ext_vector_type(4))) float f32x4;

static __device__ __forceinline__ float sigmoidf_(float x) {
  return 1.f / (1.f + __expf(-x));
}

// Split pair (x0,x1) -> packed bf16 hi (RN) and lo (exact residual, truncated).
static __device__ __forceinline__ void split2(float x0, float x1,
                                              unsigned& hp, unsigned& lp) {
  unsigned u0 = __float_as_uint(x0), u1 = __float_as_uint(x1);
  unsigned r0 = u0 + 0x7fffu + ((u0 >> 16) & 1u);
  unsigned r1 = u1 + 0x7fffu + ((u1 >> 16) & 1u);
  hp = __builtin_amdgcn_perm(r1, r0, 0x07060302u);
  float l0 = x0 - __uint_as_float(r0 & 0xffff0000u);
  float l1 = x1 - __uint_as_float(r1 & 0xffff0000u);
  lp = __builtin_amdgcn_perm(__float_as_uint(l1), __float_as_uint(l0),
                             0x07060302u);
}

// ---------------------------------------------------------------------------
// bf16x3-split MFMA NT GEMM, weights pre-split to bf16 hi/lo (dense, ld=K).
// A fp32 (split in staging). C ≈ Ah·Wh + Ah·Wl + Al·Wh. Tile 128x64, BK=32.
// XCD-aware swizzle: blocks sharing A-rows (same by) get linear IDs congruent
// mod 8 -> same XCD -> A fetched once per XCD instead of 8x across XCDs.
// K-loop software-pipelined: next tile's globals prefetched after barrier 2.
// act: 0 none, 1 softplus, 2 sigmoid, 3 dt-fused, 4 heads-fused.
// ---------------------------------------------------------------------------
__global__ void __launch_bounds__(256) gemm_bx3(
    const float* __restrict__ A, int lda,
    const unsigned short* __restrict__ Wh, const unsigned short* __restrict__ Wl,
    const float* __restrict__ bias,
    const float* __restrict__ bbias,
    float* __restrict__ C, int ldc,
    int K, int act,
    float* __restrict__ aux1, float* __restrict__ aux2)
{
  __shared__ unsigned short Ah[128 * KP], Al[128 * KP];
  __shared__ unsigned short Bh[64 * KP],  Bl[64 * KP];
  const int tid = threadIdx.x;

  int bx = blockIdx.x, by = blockIdx.y;
  {
    int gx = gridDim.x, gy = gridDim.y;
    if ((gy & 7) == 0) {                     // swizzle when gy % 8 == 0
      int id = by * gx + bx;
      int slot = id >> 3, ypg = gy >> 3;
      by = (id & 7) * ypg + (slot % ypg);
      bx = slot / ypg;
    }
  }
  const int m0 = by << 7;
  const int n0 = bx << 6;

  const int lane = tid & 63;
  const int wm = ((tid >> 6) & 1) << 6;
  const int wn = (tid >> 7) << 5;
  const int lr = lane & 15, quad = lane >> 4;

  const int arow = tid >> 1, akoff = (tid & 1) << 4;
  const float* ap = A + (size_t)(m0 + arow) * lda + akoff;
  const int brow = tid >> 2, bkoff = (tid & 3) << 3;
  const unsigned short* wph = Wh + (size_t)(n0 + brow) * K + bkoff;
  const unsigned short* wpl = Wl + (size_t)(n0 + brow) * K + bkoff;

  f32x4 acc[4][2];
#pragma unroll
  for (int mt = 0; mt < 4; ++mt)
#pragma unroll
    for (int nt = 0; nt < 2; ++nt)
      acc[mt][nt] = (f32x4){0.f, 0.f, 0.f, 0.f};

  // preload k0 = 0
  float4 av[4];
  uint4 bhC, blC;
#pragma unroll
  for (int i = 0; i < 4; ++i) av[i] = *(const float4*)(ap + (i << 2));
  bhC = *(const uint4*)(wph);
  blC = *(const uint4*)(wpl);

  for (int k0 = 0; k0 < K; k0 += 32) {
    __syncthreads();
    {
      float af[16] = {av[0].x, av[0].y, av[0].z, av[0].w,
                      av[1].x, av[1].y, av[1].z, av[1].w,
                      av[2].x, av[2].y, av[2].z, av[2].w,
                      av[3].x, av[3].y, av[3].z, av[3].w};
#pragma unroll
      for (int g = 0; g < 2; ++g) {
        unsigned h4[4], l4[4];
#pragma unroll
        for (int p = 0; p < 4; ++p)
          split2(af[g * 8 + 2 * p], af[g * 8 + 2 * p + 1], h4[p], l4[p]);
        *(uint4*)&Ah[arow * KP + akoff + (g << 3)] = make_uint4(h4[0], h4[1], h4[2], h4[3]);
        *(uint4*)&Al[arow * KP + akoff + (g << 3)] = make_uint4(l4[0], l4[1], l4[2], l4[3]);
      }
    }
    *(uint4*)&Bh[brow * KP + bkoff] = bhC;
    *(uint4*)&Bl[brow * KP + bkoff] = blC;
    __syncthreads();

    // prefetch next tile (overlaps frag reads + MFMA below)
    if (k0 + 32 < K) {
      int kn = k0 + 32;
#pragma unroll
      for (int i = 0; i < 4; ++i) av[i] = *(const float4*)(ap + kn + (i << 2));
      bhC = *(const uint4*)(wph + kn);
      blC = *(const uint4*)(wpl + kn);
    }

    short8 fah[4], fal[4], fbh[2], fbl[2];
#pragma unroll
    for (int mt = 0; mt < 4; ++mt) {
      int r = (wm + mt * 16 + lr) * KP + quad * 8;
      fah[mt] = *(const short8*)&Ah[r];
      fal[mt] = *(const short8*)&Al[r];
    }
#pragma unroll
    for (int nt = 0; nt < 2; ++nt) {
      int r = (wn + nt * 16 + lr) * KP + quad * 8;
      fbh[nt] = *(const short8*)&Bh[r];
      fbl[nt] = *(const short8*)&Bl[r];
    }
#pragma unroll
    for (int mt = 0; mt < 4; ++mt)
#pragma unroll
      for (int nt = 0; nt < 2; ++nt) {
        acc[mt][nt] = __builtin_amdgcn_mfma_f32_16x16x32_bf16(
            fah[mt], fbl[nt], acc[mt][nt], 0, 0, 0);
        acc[mt][nt] = __builtin_amdgcn_mfma_f32_16x16x32_bf16(
            fal[mt], fbh[nt], acc[mt][nt], 0, 0, 0);
        acc[mt][nt] = __builtin_amdgcn_mfma_f32_16x16x32_bf16(
            fah[mt], fbh[nt], acc[mt][nt], 0, 0, 0);
      }
  }

  const int bb = m0 >> 10;
#pragma unroll
  for (int mt = 0; mt < 4; ++mt)
#pragma unroll
    for (int nt = 0; nt < 2; ++nt) {
      int ncol = n0 + wn + nt * 16 + lr;
      float bv = bias ? bias[ncol] : 0.f;
      if (bbias) bv += bbias[(size_t)bb * ldc + ncol];
#pragma unroll
      for (int reg = 0; reg < 4; ++reg) {
        int m = m0 + wm + mt * 16 + quad * 4 + reg;
        float v = acc[mt][nt][reg] + bv;
        if (act == 0) {
          C[(size_t)m * ldc + ncol] = v;
        } else if (act == 1) {
          C[(size_t)m * ldc + ncol] = (v > 20.f) ? v : log1pf(__expf(v));
        } else if (act == 2) {
          C[(size_t)m * ldc + ncol] = sigmoidf_(v);
        } else if (act == 3) {
          if (ncol < 512)      C[(size_t)m * 512 + ncol] = (v > 20.f) ? v : log1pf(__expf(v));
          else if (ncol < 528) aux1[(size_t)m * 16 + (ncol - 512)] = v;
          else if (ncol < 544) aux2[(size_t)m * 16 + (ncol - 528)] = v;
        } else {               // act == 4
          if (ncol < 512)      C[(size_t)m * 512 + ncol] = v;
          else if (ncol < 520) aux1[(size_t)m * 8 + (ncol - 512)] = v;
          else if (ncol < 540) aux2[(size_t)m * 20 + (ncol - 520)] = v;
        }
      }
    }
}

// ---------------------------------------------------------------------------
// Weight conversion bodies (device helpers) + merged per-phase kernels.
// ---------------------------------------------------------------------------
static __device__ __forceinline__ void wcvt_body(
    int gid, const float* __restrict__ W, int ldw,
    unsigned short* __restrict__ hi, unsigned short* __restrict__ lo)
{
  int base = gid << 3;
  int r = base >> 9, c = base & 511;
  const float* p = W + (size_t)r * ldw + c;
  float4 a0 = *(const float4*)p, a1 = *(const float4*)(p + 4);
  float af[8] = {a0.x, a0.y, a0.z, a0.w, a1.x, a1.y, a1.z, a1.w};
  unsigned h4[4], l4[4];
#pragma unroll
  for (int p2 = 0; p2 < 4; ++p2) split2(af[2 * p2], af[2 * p2 + 1], h4[p2], l4[p2]);
  *(uint4*)&hi[(size_t)r * 512 + c] = make_uint4(h4[0], h4[1], h4[2], h4[3]);
  *(uint4*)&lo[(size_t)r * 512 + c] = make_uint4(l4[0], l4[1], l4[2], l4[3]);
}

static __device__ __forceinline__ void pack_body(
    int gid, unsigned short* __restrict__ hi, unsigned short* __restrict__ lo,
    float* __restrict__ bd,
    const float* __restrict__ w0, const float* __restrict__ b0,
    const float* __restrict__ w1, const float* __restrict__ b1,
    const float* __restrict__ w2, const float* __restrict__ b2,
    int n1, int n2)
{
  int base = gid << 3;
  int r = base >> 9, c = base & 511;
  const float* src = nullptr;
  if (r < 512)                 src = w0 + (size_t)r * 512 + c;
  else if (r < 512 + n1)       src = w1 + (size_t)(r - 512) * 512 + c;
  else if (r < 512 + n1 + n2)  src = w2 + (size_t)(r - 512 - n1) * 512 + c;
  float af[8] = {0.f};
  if (src) {
    float4 a0 = *(const float4*)src, a1 = *(const float4*)(src + 4);
    af[0]=a0.x; af[1]=a0.y; af[2]=a0.z; af[3]=a0.w;
    af[4]=a1.x; af[5]=a1.y; af[6]=a1.z; af[7]=a1.w;
  }
  unsigned h4[4], l4[4];
#pragma unroll
  for (int p2 = 0; p2 < 4; ++p2) split2(af[2 * p2], af[2 * p2 + 1], h4[p2], l4[p2]);
  *(uint4*)&hi[(size_t)r * 512 + c] = make_uint4(h4[0], h4[1], h4[2], h4[3]);
  *(uint4*)&lo[(size_t)r * 512 + c] = make_uint4(l4[0], l4[1], l4[2], l4[3]);
  if (c == 0) {
    float bvv = 0.f;
    if (r < 512)                 bvv = b0[r];
    else if (r < 512 + n1)       bvv = b1[r - 512];
    else if (r < 512 + n1 + n2)  bvv = b2[r - 512 - n1];
    bd[r] = bvv;
  }
}

// Per-layer conversion A: Win (256 blocks) + Wdt/WB/WC pack (144 blocks)
__global__ void cvt_layerA(const float* __restrict__ Win_l,
                           const float* __restrict__ Wdt_l, const float* __restrict__ b_dt_l,
                           const float* __restrict__ WB_l, const float* __restrict__ b_B_l,
                           const float* __restrict__ WC_l, const float* __restrict__ b_C_l,
                           unsigned short* WinH, unsigned short* WinL,
                           unsigned short* WpkH, unsigned short* WpkL, float* bpk)
{
  int blk = blockIdx.x;
  if (blk < 256)
    wcvt_body(blk * 256 + threadIdx.x, Win_l, 512, WinH, WinL);
  else
    pack_body((blk - 256) * 256 + threadIdx.x, WpkH, WpkL, bpk,
              Wdt_l, b_dt_l, WB_l, b_B_l, WC_l, b_C_l, 16, 16);
}

// Per-layer conversion B: Wout (128) + Wg first-half (128)
__global__ void cvt_layerB(const float* __restrict__ Wout_l,
                           const float* __restrict__ Wg_l,
                           unsigned short* WsqH, unsigned short* WsqL,
                           unsigned short* WgH, unsigned short* WgL)
{
  int blk = blockIdx.x;
  if (blk < 128)
    wcvt_body(blk * 256 + threadIdx.x, Wout_l, 512, WsqH, WsqL);
  else
    wcvt_body((blk - 128) * 256 + threadIdx.x, Wg_l, 1024, WgH, WgL);
}

// Heads conversion: pack(Wq,Wa,Wv) (144) + Wk (128)
__global__ void cvt_heads(const float* __restrict__ Wq, const float* __restrict__ b_q,
                          const float* __restrict__ Wa, const float* __restrict__ b_a,
                          const float* __restrict__ Wv, const float* __restrict__ b_v,
                          const float* __restrict__ Wk,
                          unsigned short* WpkH, unsigned short* WpkL, float* bpk,
                          unsigned short* WsqH, unsigned short* WsqL)
{
  int blk = blockIdx.x;
  if (blk < 144)
    pack_body(blk * 256 + threadIdx.x, WpkH, WpkL, bpk,
              Wq, b_q, Wa, b_a, Wv, b_v, NA_, MV_);
  else
    wcvt_body((blk - 144) * 256 + threadIdx.x, Wk, 512, WsqH, WsqL);
}

// Prep-phase single-weight split
__global__ void wcvt(const float* __restrict__ W, int ldw,
                     unsigned short* __restrict__ hi, unsigned short* __restrict__ lo)
{
  wcvt_body(blockIdx.x * 256 + threadIdx.x, W, ldw, hi, lo);
}

// ---------------------------------------------------------------------------
// Batched scores: out[b,t,s] = dot(q,k)/sqrt(D); masked -> -1e30 (finite).
// ---------------------------------------------------------------------------
#define BM 64
#define BN 64
#define BK 16

__global__ void __launch_bounds__(256) scores_kernel(
    const float* __restrict__ q, const float* __restrict__ kmat,
    const int* __restrict__ mask, float* __restrict__ out)
{
  __shared__ __align__(16) float As[BK][BM + 4];
  __shared__ __align__(16) float Ws[BK][BN + 4];
  const int b = blockIdx.z;
  const float* A = q + (size_t)b * T_ * D_;
  const float* W = kmat + (size_t)b * S_ * D_;
  const int tid = threadIdx.x;
  const int m0 = blockIdx.y * BM;
  const int n0 = blockIdx.x * BN;
  const int tx = tid & 15, ty = tid >> 4;
  const int lr = tid >> 2;
  const int lk = (tid & 3) << 2;
  float acc[4][4] = {{0.f}};
  const float* aptr = A + (size_t)(m0 + lr) * D_ + lk;
  const float* wptr = W + (size_t)(n0 + lr) * D_ + lk;

  for (int k0 = 0; k0 < D_; k0 += BK) {
    float4 av = *(const float4*)(aptr + k0);
    float4 wv = *(const float4*)(wptr + k0);
    __syncthreads();
    As[lk + 0][lr] = av.x; As[lk + 1][lr] = av.y;
    As[lk + 2][lr] = av.z; As[lk + 3][lr] = av.w;
    Ws[lk + 0][lr] = wv.x; Ws[lk + 1][lr] = wv.y;
    Ws[lk + 2][lr] = wv.z; Ws[lk + 3][lr] = wv.w;
    __syncthreads();
#pragma unroll
    for (int kk = 0; kk < BK; ++kk) {
      float4 a4 = *(const float4*)&As[kk][ty << 2];
      float4 b4 = *(const float4*)&Ws[kk][tx << 2];
      float a_[4] = {a4.x, a4.y, a4.z, a4.w};
      float b_[4] = {b4.x, b4.y, b4.z, b4.w};
#pragma unroll
      for (int i = 0; i < 4; ++i)
#pragma unroll
        for (int j = 0; j < 4; ++j)
          acc[i][j] = fmaf(a_[i], b_[j], acc[i][j]);
    }
  }

  const float scale = 0.044194173824159216f;
#pragma unroll
  for (int i = 0; i < 4; ++i) {
    int t = m0 + (ty << 2) + i;
#pragma unroll
    for (int j = 0; j < 4; ++j) {
      int s = n0 + (tx << 2) + j;
      float v = acc[i][j] * scale;
      if (mask[b * S_ + s] == 0) v = -1e30f;
      out[((size_t)(b * T_ + t)) * S_ + s] = v;
    }
  }
}

// ---------------------------------------------------------------------------
// Small helpers
// ---------------------------------------------------------------------------
__global__ void gemm_small(const float* __restrict__ A, int lda,
                           const float* __restrict__ W, int ldw,
                           const float* __restrict__ bias,
                           float* __restrict__ C, int ldc,
                           int MN, int Ncols, int K)
{
  int gid = blockIdx.x * 256 + threadIdx.x;
  if (gid >= MN) return;
  int r = gid / Ncols, o = gid - r * Ncols;
  const float4* a = (const float4*)(A + (size_t)r * lda);
  const float4* w = (const float4*)(W + (size_t)o * ldw);
  float acc = bias ? bias[o] : 0.f;
  int K4 = K >> 2;
  for (int k = 0; k < K4; ++k) {
    float4 av = a[k], wv = w[k];
    acc = fmaf(av.x, wv.x, fmaf(av.y, wv.y, fmaf(av.z, wv.z, fmaf(av.w, wv.w, acc))));
  }
  C[(size_t)r * ldc + o] = acc;
}

__global__ void ctx_kernel(const float* __restrict__ msum, const float* __restrict__ Wm,
                           const float* __restrict__ b_m, float* __restrict__ ctxv)
{
  int gid = blockIdx.x * 256 + threadIdx.x;
  int l = gid >> 12, b = (gid >> 9) & 7, dd = gid & 511;
  const float4* a = (const float4*)(msum + b * 512);
  const float4* w = (const float4*)(Wm + ((size_t)l * 512 + dd) * 512);
  float acc = b_m[l * 512 + dd];
  for (int k = 0; k < 128; ++k) {
    float4 av = a[k], wv = w[k];
    acc = fmaf(av.x, wv.x, fmaf(av.y, wv.y, fmaf(av.z, wv.z, fmaf(av.w, wv.w, acc))));
  }
  ctxv[gid] = acc;
}

__global__ void gctx_kernel(const float* __restrict__ ctxv, const float* __restrict__ Wg,
                            const float* __restrict__ b_g, float* __restrict__ gctx)
{
  int gid = blockIdx.x * 256 + threadIdx.x;
  int l = gid >> 12, b = (gid >> 9) & 7, dd = gid & 511;
  const float4* a = (const float4*)(ctxv + ((size_t)l * 8 + b) * 512);
  const float4* w = (const float4*)(Wg + ((size_t)l * 512 + dd) * 1024 + 512);
  float acc = b_g[l * 512 + dd];
  for (int k = 0; k < 128; ++k) {
    float4 av = a[k], wv = w[k];
    acc = fmaf(av.x, wv.x, fmaf(av.y, wv.y, fmaf(av.z, wv.z, fmaf(av.w, wv.w, acc))));
  }
  gctx[gid] = acc;
}

__global__ void __launch_bounds__(256) transpose512(
    const float* __restrict__ A, float* __restrict__ At)
{
  __shared__ float tl[32][33];
  int i0 = blockIdx.y * 32, j0 = blockIdx.x * 32;
  int li = threadIdx.x & 31, lj = threadIdx.x >> 5;
#pragma unroll
  for (int k = 0; k < 4; ++k)
    tl[lj * 4 + k][li] = A[(size_t)(i0 + lj * 4 + k) * 512 + j0 + li];
  __syncthreads();
#pragma unroll
  for (int k = 0; k < 4; ++k)
    At[(size_t)(j0 + lj * 4 + k) * 512 + i0 + li] = tl[li][lj * 4 + k];
}

__global__ void memsum_kernel(const float* __restrict__ mem, float* __restrict__ out)
{
  int b = blockIdx.x >> 1;
  int d = ((blockIdx.x & 1) << 8) + threadIdx.x;
  const float* p = mem + (size_t)b * MM_ * D_ + d;
  float s = 0.f;
  for (int m = 0; m < MM_; ++m) s += p[(size_t)m * D_];
  out[b * D_ + d] = s * (1.f / MM_);
}

__global__ void combine_kernel(float* __restrict__ h, const float* __restrict__ Psym,
                               const float* __restrict__ Pact,
                               const float* __restrict__ Pvar, const float* __restrict__ b2,
                               const float* __restrict__ bcomb,
                               const int* __restrict__ ta, const int* __restrict__ tg)
{
  int i = blockIdx.x * 256 + threadIdx.x;
  int r = i >> 9, j = i & 511;
  int t = r & (T_ - 1);
  int a = t ? ta[r - 1] : 0;
  float val = Pact[a * D_ + j] + bcomb[j];
  if (a == 1 || a == 2) {
    int g = t ? tg[r - 1] : 0;
    g = g < 0 ? 0 : (g > S_ - 1 ? S_ - 1 : g);
    val += Psym[((size_t)(r >> 10) * S_ + g) * D_ + j] + b2[j];
  } else if (a == 3) {
    int g = t ? tg[r - 1] : 0;
    g = g < 0 ? 0 : (g > MV_ - 1 ? MV_ - 1 : g);
    val += Pvar[g * D_ + j];
  }
  h[i] = val;
}

// ---------------------------------------------------------------------------
// Chunked selective scan (round-8 structure: transposed LDS staging,
// registerized dt/x, deferred reduce + fused epilogue in pass3).
// ---------------------------------------------------------------------------
__global__ void __launch_bounds__(128) scan_pass1(
    const float* __restrict__ xz, const float* __restrict__ dts,
    const float* __restrict__ Bmv, const float* __restrict__ Alog,
    float* __restrict__ aprod, float* __restrict__ hend)
{
  __shared__ __align__(16) float sdtT[DB][TP];
  __shared__ __align__(16) float sxT[DB][TP];
  __shared__ __align__(16) float sB[TS][16];
  const int tid = threadIdx.x;
  const int n = tid & 15, dl = tid >> 4;
  const int c = blockIdx.x, db = blockIdx.y, b = blockIdx.z;
  const int d = (db << 3) + dl;
  const int t0 = c * LCH;
  const int lrow = tid >> 2, lc2 = (tid & 3) << 1, bc4 = (tid & 3) << 2;

  float An = -__expf(Alog[d * N_ + n]);
  float hst = 0.f, dsum = 0.f;

  for (int tt = 0; tt < LCH; tt += TS) {
    __syncthreads();
    {
      size_t gr = (size_t)b * T_ + t0 + tt + lrow;
      float2 dt2 = *(const float2*)&dts[(gr << 9) + (db << 3) + lc2];
      float2 x2  = *(const float2*)&xz[(gr << 10) + (db << 3) + lc2];
      sdtT[lc2][lrow] = dt2.x; sdtT[lc2 + 1][lrow] = dt2.y;
      sxT[lc2][lrow]  = x2.x;  sxT[lc2 + 1][lrow]  = x2.y;
      *(float4*)&sB[lrow][bc4] = *(const float4*)&Bmv[gr * N_ + bc4];
    }
    __syncthreads();
    float dtr[TS], xr[TS];
#pragma unroll
    for (int qv = 0; qv < TS / 4; ++qv) {
      *(float4*)&dtr[qv << 2] = *(const float4*)&sdtT[dl][qv << 2];
      *(float4*)&xr[qv << 2]  = *(const float4*)&sxT[dl][qv << 2];
    }
#pragma unroll
    for (int s = 0; s < TS; ++s) {
      float Bv = sB[s][n];
      float dA = __expf(An * dtr[s]);
      hst = fmaf(dA, hst, dtr[s] * xr[s] * Bv);
      dsum += dtr[s];
    }
  }
  size_t idx = (size_t)c * (B_ * D_ * N_) + ((size_t)b * D_ + d) * N_ + n;
  aprod[idx] = __expf(An * dsum);
  hend[idx]  = hst;
}

__global__ void scan_pass2(const float* __restrict__ aprod, float* __restrict__ hs)
{
  int g = blockIdx.x * 256 + threadIdx.x;
  float prev = 0.f;
  for (int c = 0; c < TC; ++c) {
    size_t idx = (size_t)c * (B_ * D_ * N_) + g;
    float a = aprod[idx], he = hs[idx];
    hs[idx] = prev;
    prev = fmaf(a, prev, he);
  }
}

#define HPAD 20

__global__ void __launch_bounds__(128) scan_pass3(
    const float* __restrict__ xz, float* __restrict__ dy,
    const float* __restrict__ Bmv, const float* __restrict__ Cmv,
    const float* __restrict__ Alog, const float* __restrict__ hstart,
    const float* __restrict__ Dp)
{
  __shared__ __align__(16) float sdtT[DB][TP];
  __shared__ __align__(16) float sxT[DB][TP];
  __shared__ __align__(16) float szT[DB][TP];
  __shared__ __align__(16) float sB[TS][16];
  __shared__ __align__(16) float sC[TS][16];
  __shared__ __align__(16) float sterm[128][HPAD];
  const int tid = threadIdx.x;
  const int n = tid & 15, dl = tid >> 4;
  const int c = blockIdx.x, db = blockIdx.y, b = blockIdx.z;
  const int d = (db << 3) + dl;
  const int t0 = c * LCH;
  const int lrow = tid >> 2, lc2 = (tid & 3) << 1, bc4 = (tid & 3) << 2;
  const int rsi = tid >> 3, rdl = tid & 7;

  float An = -__expf(Alog[d * N_ + n]);
  float Dpr = Dp[(db << 3) + rdl];
  size_t sidx = (size_t)c * (B_ * D_ * N_) + ((size_t)b * D_ + d) * N_ + n;
  float hst = hstart[sidx];

  for (int tt = 0; tt < LCH; tt += TS) {
    __syncthreads();
    {
      size_t gr = (size_t)b * T_ + t0 + tt + lrow;
      float2 dt2 = *(const float2*)&dy[(gr << 9) + (db << 3) + lc2];
      float2 x2  = *(const float2*)&xz[(gr << 10) + (db << 3) + lc2];
      float2 z2  = *(const float2*)&xz[(gr << 10) + D_ + (db << 3) + lc2];
      sdtT[lc2][lrow] = dt2.x; sdtT[lc2 + 1][lrow] = dt2.y;
      sxT[lc2][lrow]  = x2.x;  sxT[lc2 + 1][lrow]  = x2.y;
      szT[lc2][lrow]  = z2.x;  szT[lc2 + 1][lrow]  = z2.y;
      *(float4*)&sB[lrow][bc4] = *(const float4*)&Bmv[gr * N_ + bc4];
      *(float4*)&sC[lrow][bc4] = *(const float4*)&Cmv[gr * N_ + bc4];
    }
    __syncthreads();
    float dtr[TS], xr[TS];
#pragma unroll
    for (int qv = 0; qv < TS / 4; ++qv) {
      *(float4*)&dtr[qv << 2] = *(const float4*)&sdtT[dl][qv << 2];
      *(float4*)&xr[qv << 2]  = *(const float4*)&sxT[dl][qv << 2];
    }
#pragma unroll
    for (int half = 0; half < 2; ++half) {
      const int hs = half << 4;
#pragma unroll
      for (int si = 0; si < 16; ++si) {
        int s = hs + si;
        float Bv = sB[s][n], Cv = sC[s][n];
        float dA = __expf(An * dtr[s]);
        hst = fmaf(dA, hst, dtr[s] * xr[s] * Bv);
        sterm[(si << 3) + dl][n] = hst * Cv;
      }
      __syncthreads();
      {
        float4 t0v = *(const float4*)&sterm[tid][0];
        float4 t1v = *(const float4*)&sterm[tid][4];
        float4 t2v = *(const float4*)&sterm[tid][8];
        float4 t3v = *(const float4*)&sterm[tid][12];
        float s16 = ((t0v.x + t0v.y) + (t0v.z + t0v.w))
                  + ((t1v.x + t1v.y) + (t1v.z + t1v.w))
                  + ((t2v.x + t2v.y) + (t2v.z + t2v.w))
                  + ((t3v.x + t3v.y) + (t3v.z + t3v.w));
        float zv = szT[rdl][hs + rsi];
        float xv = sxT[rdl][hs + rsi];
        float yv = (s16 + Dpr * xv) * (zv * sigmoidf_(zv));
        __syncthreads();
        sdtT[rdl][hs + rsi] = yv;
      }
      __syncthreads();
    }
    {
      size_t gr = (size_t)b * T_ + t0 + tt + lrow;
      float2 y2;
      y2.x = sdtT[lc2][lrow];
      y2.y = sdtT[lc2 + 1][lrow];
      *(float2*)&dy[(gr << 9) + (db << 3) + lc2] = y2;
    }
  }
}

// LayerNorm, one wave per row. mode 0: v = h + add; mode 1: v = h + add*ctx[b]
__global__ void __launch_bounds__(256) ln_kernel(
    float* __restrict__ h, const float* __restrict__ add,
    const float* __restrict__ ctx,
    const float* __restrict__ gw, const float* __restrict__ bw, int mode)
{
  int r = (blockIdx.x << 2) + (threadIdx.x >> 6);
  int lane = threadIdx.x & 63;
  int b = r >> 10;
  size_t base = (size_t)r * D_;
  float v[8];
#pragma unroll
  for (int k = 0; k < 8; ++k) {
    int j = lane + (k << 6);
    float x = h[base + j];
    float a = add[base + j];
    v[k] = mode ? fmaf(a, ctx[b * D_ + j], x) : (x + a);
  }
  float s = 0.f;
#pragma unroll
  for (int k = 0; k < 8; ++k) s += v[k];
#pragma unroll
  for (int o = 1; o < 64; o <<= 1) s += __shfl_xor(s, o, 64);
  float mean = s * (1.f / D_);
  float vs = 0.f;
#pragma unroll
  for (int k = 0; k < 8; ++k) { float dv = v[k] - mean; vs = fmaf(dv, dv, vs); }
#pragma unroll
  for (int o = 1; o < 64; o <<= 1) vs += __shfl_xor(vs, o, 64);
  float inv = 1.0f / sqrtf(vs * (1.f / D_) + 1e-5f);
#pragma unroll
  for (int k = 0; k < 8; ++k) {
    int j = lane + (k << 6);
    h[base + j] = (v[k] - mean) * inv * gw[j] + bw[j];
  }
}

// ---------------------------------------------------------------------------
extern "C" void kernel_launch(void* const* d_in, const int* in_sizes, int n_in,
                              void* d_out, int out_size, void* d_ws, size_t ws_size,
                              hipStream_t stream)
{
  const float* symbol_embeds = (const float*)d_in[0];
  const float* memory_       = (const float*)d_in[1];
  const float* action_embed  = (const float*)d_in[2];
  const float* W_arg  = (const float*)d_in[3];
  const float* b_arg  = (const float*)d_in[4];
  const float* var_embed = (const float*)d_in[5];
  const float* W_comb = (const float*)d_in[6];
  const float* b_comb = (const float*)d_in[7];
  const float* Win  = (const float*)d_in[8];
  const float* b_in = (const float*)d_in[9];
  const float* Wdt  = (const float*)d_in[10];
  const float* b_dt = (const float*)d_in[11];
  const float* Alog = (const float*)d_in[12];
  const float* WB   = (const float*)d_in[13];
  const float* b_B  = (const float*)d_in[14];
  const float* WC   = (const float*)d_in[15];
  const float* b_C  = (const float*)d_in[16];
  const float* Dp   = (const float*)d_in[17];
  const float* Wout = (const float*)d_in[18];
  const float* b_out= (const float*)d_in[19];
  const float* ssm_g= (const float*)d_in[20];
  const float* ssm_b= (const float*)d_in[21];
  const float* Wm   = (const float*)d_in[22];
  const float* b_m  = (const float*)d_in[23];
  const float* Wg   = (const float*)d_in[24];
  const float* b_g  = (const float*)d_in[25];
  const float* cn_g = (const float*)d_in[26];
  const float* cn_b = (const float*)d_in[27];
  const float* Wa   = (const float*)d_in[28];
  const float* b_a  = (const float*)d_in[29];
  const float* Wq   = (const float*)d_in[30];
  const float* b_q  = (const float*)d_in[31];
  const float* Wk   = (const float*)d_in[32];
  const float* b_k  = (const float*)d_in[33];
  const float* Wv   = (const float*)d_in[34];
  const float* b_v  = (const float*)d_in[35];
  const int* ta     = (const int*)d_in[36];
  const int* tg     = (const int*)d_in[37];
  const int* smask  = (const int*)d_in[38];
  (void)in_sizes; (void)n_in; (void)out_size; (void)ws_size;

  // ---- workspace: exactly 64 MB ----
  float* ws = (float*)d_ws;
  float* xz = ws;                               // R*1024
  float* dy = xz + (size_t)R_ * 1024;           // R*512
  float* h  = dy + (size_t)R_ * 512;            // R*512
  float* Psym = xz;

  // ---- d_out scratch (1,277,952 floats) ----
  float* out     = (float*)d_out;
  float* out_act = out;
  float* out_sc  = out + (size_t)R_ * NA_;
  float* out_var = out + (size_t)R_ * (NA_ + S_);

  float* Bmv  = out;                      // 131072
  float* Cmv  = Bmv  + 131072;            // 131072
  float* aprd = Cmv  + 131072;            // 262144
  float* hend = aprd + 262144;            // 262144
  float* Wpk  = hend + 262144;            // 294912
  float* bpk  = Wpk  + 294912;            // 576
  float* msum = bpk  + 576;               // 4096
  float* ctxv = msum + 4096;              // 12288
  float* gctx = ctxv + 12288;             // 12288

  unsigned short* WpkH = (unsigned short*)Wpk;
  unsigned short* WpkL = WpkH + 294912;
  unsigned short* WinH = (unsigned short*)aprd;
  unsigned short* WinL = WinH + 524288;
  unsigned short* WsqH = (unsigned short*)aprd;
  unsigned short* WsqL = WsqH + 262144;
  unsigned short* WgH  = (unsigned short*)hend;
  unsigned short* WgL  = WgH + 262144;
  unsigned short* PrepH = (unsigned short*)Bmv;
  unsigned short* PrepL = PrepH + 262144;

  float* Pact = aprd;
  float* Pvar = Pact + 4096;
  float* b2   = Pvar + 10240;
  float* M2   = hend;
  float* WargT= Wpk;

  dim3 blk(256), blk128(128);

  // ---- precompute ----
  memsum_kernel<<<16, blk, 0, stream>>>(memory_, msum);
  gemm_small<<<16, blk, 0, stream>>>(action_embed, 512, W_comb, 1024, nullptr,
                                     Pact, 512, 8 * 512, 512, 512);
  gemm_small<<<40, blk, 0, stream>>>(var_embed, 512, W_comb + 512, 1024, nullptr,
                                     Pvar, 512, 20 * 512, 512, 512);
  gemm_small<<<2, blk, 0, stream>>>(b_arg, 512, W_comb + 512, 1024, nullptr,
                                    b2, 512, 512, 512, 512);
  ctx_kernel<<<48, blk, 0, stream>>>(msum, Wm, b_m, ctxv);
  gctx_kernel<<<48, blk, 0, stream>>>(ctxv, Wg, b_g, gctx);
  transpose512<<<dim3(16, 16), blk, 0, stream>>>(W_arg, WargT);
  wcvt<<<128, blk, 0, stream>>>(WargT, 512, PrepH, PrepL);
  gemm_bx3<<<dim3(8, 4), blk, 0, stream>>>(W_comb + 512, 1024, PrepH, PrepL,
                                           nullptr, nullptr, M2, 512, 512, 0,
                                           nullptr, nullptr);
  wcvt<<<128, blk, 0, stream>>>(M2, 512, PrepH, PrepL);
  gemm_bx3<<<dim3(8, 8), blk, 0, stream>>>(symbol_embeds, 512, PrepH, PrepL,
                                           nullptr, nullptr, Psym, 512, 512, 0,
                                           nullptr, nullptr);
  combine_kernel<<<R_ * 512 / 256, blk, 0, stream>>>(h, Psym, Pact, Pvar, b2,
                                                     b_comb, ta, tg);

  // ---- layers ----
  for (int l = 0; l < 3; ++l) {
    const float* Win_l  = Win  + (size_t)l * 1024 * 512;
    const float* b_in_l = b_in + l * 1024;
    const float* Wdt_l  = Wdt  + (size_t)l * 512 * 512;
    const float* b_dt_l = b_dt + l * 512;
    const float* Alog_l = Alog + (size_t)l * 512 * 16;
    const float* WB_l   = WB   + (size_t)l * 16 * 512;
    const float* b_B_l  = b_B  + l * 16;
    const float* WC_l   = WC   + (size_t)l * 16 * 512;
    const float* b_C_l  = b_C  + l * 16;
    const float* Dp_l   = Dp   + l * 512;
    const float* Wout_l = Wout + (size_t)l * 512 * 512;
    const float* b_out_l= b_out+ l * 512;
    const float* ssm_g_l= ssm_g+ l * 512;
    const float* ssm_b_l= ssm_b+ l * 512;
    const float* Wg_l   = Wg   + (size_t)l * 512 * 1024;
    const float* cn_g_l = cn_g + l * 512;
    const float* cn_b_l = cn_b + l * 512;

    cvt_layerA<<<400, blk, 0, stream>>>(Win_l, Wdt_l, b_dt_l, WB_l, b_B_l,
                                        WC_l, b_C_l, WinH, WinL, WpkH, WpkL, bpk);
    // xz = h @ Win^T + b_in
    gemm_bx3<<<dim3(16, 64), blk, 0, stream>>>(h, 512, WinH, WinL,
                                               b_in_l, nullptr, xz, 1024, 512, 0,
                                               nullptr, nullptr);
    // fused dt/B/C
    gemm_bx3<<<dim3(9, 64), blk, 0, stream>>>(xz, 1024, WpkH, WpkL,
                                              bpk, nullptr, dy, 512, 512, 3,
                                              Bmv, Cmv);
    // chunked scan
    scan_pass1<<<dim3(TC, D_ / DB, B_), blk128, 0, stream>>>(xz, dy, Bmv, Alog_l,
                                                             aprd, hend);
    scan_pass2<<<B_ * D_ * N_ / 256, blk, 0, stream>>>(aprd, hend);
    scan_pass3<<<dim3(TC, D_ / DB, B_), blk128, 0, stream>>>(xz, dy, Bmv, Cmv,
                                                             Alog_l, hend, Dp_l);
    cvt_layerB<<<256, blk, 0, stream>>>(Wout_l, Wg_l, WsqH, WsqL, WgH, WgL);
    // resid = dy @ Wout^T + b_out -> xz
    gemm_bx3<<<dim3(8, 64), blk, 0, stream>>>(dy, 512, WsqH, WsqL,
                                              b_out_l, nullptr, xz, 512, 512, 0,
                                              nullptr, nullptr);
    ln_kernel<<<2048, blk, 0, stream>>>(h, xz, nullptr, ssm_g_l, ssm_b_l, 0);
    // gate = sigmoid(h @ Wg[:, :512]^T + gctx[l,b,:]) -> dy
    gemm_bx3<<<dim3(8, 64), blk, 0, stream>>>(h, 512, WgH, WgL,
                                              nullptr, gctx + l * 4096, dy, 512, 512, 2,
                                              nullptr, nullptr);
    ln_kernel<<<2048, blk, 0, stream>>>(h, dy, ctxv + l * 4096, cn_g_l, cn_b_l, 1);
  }

  // ---- heads ----
  cvt_heads<<<272, blk, 0, stream>>>(Wq, b_q, Wa, b_a, Wv, b_v, Wk,
                                     WpkH, WpkL, bpk, WsqH, WsqL);
  gemm_bx3<<<dim3(9, 64), blk, 0, stream>>>(h, 512, WpkH, WpkL,
                                            bpk, nullptr, xz, 512, 512, 4,
                                            out_act, out_var);
  gemm_bx3<<<dim3(8, 8), blk, 0, stream>>>(symbol_embeds, 512, WsqH, WsqL,
                                           b_k, nullptr, dy, 512, 512, 0,
                                           nullptr, nullptr);
  scores_kernel<<<dim3(2, 16, 8), blk, 0, stream>>>(xz, dy, smask, out_sc);
}